// Round 18
// baseline (106.127 us; speedup 1.0000x reference)
//
#include <hip/hip_runtime.h>

#define NBATCH 32
#define SEQ    2048
#define NU     512

typedef __attribute__((ext_vector_type(8))) short bf16x8;
typedef __attribute__((ext_vector_type(4))) float f32x4;

__device__ __forceinline__ short bf16_rne(float f) {
  union { float f; unsigned u; } v; v.f = f;
  unsigned r = v.u + 0x7fffu + ((v.u >> 16) & 1u);
  return (short)(r >> 16);
}

__device__ __forceinline__ unsigned pk2(float lo, float hi) {
  return __builtin_amdgcn_perm(__float_as_uint(hi), __float_as_uint(lo), 0x07060302u);
}

__device__ __forceinline__ float fast_tanh(float x) {
  float ax = __builtin_fabsf(x);
  float t  = __expf(-2.0f * ax);
  float r  = (1.0f - t) / (1.0f + t);
  return x < 0.0f ? -r : r;
}

// ---------- fused prep (identical to R17, verified) ----------
__global__ __launch_bounds__(256) void prep_all(const float* __restrict__ W,
                                                const float* __restrict__ sp,
                                                const float* __restrict__ U,
                                                const float* __restrict__ Ub,
                                                const float* __restrict__ Wb,
                                                short* __restrict__ WtSw,
                                                float* __restrict__ first) {
  __shared__ float srow[NU];
  if (blockIdx.x < 1024) {
    int idx = blockIdx.x * 256 + threadIdx.x;
    int C = idx >> 9, rem = idx & 511;
    int t = rem >> 6, up = (rem >> 3) & 7, e = rem & 7;
    int k = t * 64 + ((up ^ (C & 7)) << 3) + e;
    WtSw[idx] = bf16_rne(W[(size_t)k * NU + C]);
  } else {
    int blk = blockIdx.x - 1024;
    int b = blk >> 1, half = blk & 1, t = threadIdx.x;
    srow[t]       = sp[b * NU + t];
    srow[t + 256] = sp[b * NU + t + 256];
    __syncthreads();
    int col = half * 256 + t;
    float acc = Ub[col] + Wb[col];
    #pragma unroll 8
    for (int k = 0; k < NU; ++k) acc += srow[k] * U[(size_t)k * NU + col];
    first[b * NU + col] = acc;
  }
}

// ---------- main: R17 8-phase + register-held B fragments (24 reads/wave/K-tile) ----------
__global__ __launch_bounds__(512, 2) void attn8(
    const float* __restrict__ h,      // (65536, 512) fp32
    const short* __restrict__ WtSw,   // pre-swizzled (512 x 512) bf16
    const float* __restrict__ first,  // (B, 512) incl. U_bias + W_bias
    const float* __restrict__ V,      // (512)
    float* __restrict__ s0)           // (65536) score accumulator (pre-zeroed)
{
  __shared__ short Alds[2][256 * 64];   // 32 KB each, swizzled
  __shared__ short Blds[2][256 * 64];   // 32 KB each, swizzled

  const int tid  = threadIdx.x;
  const int lane = tid & 63;
  const int w    = tid >> 6;
  const int wr   = w >> 2, wc = w & 3;  // 2M x 4N
  const int lr   = lane & 15, hi2 = lane >> 4;

  const int bid = blockIdx.x;
  const int lb  = (bid & 7) * 64 + (bid >> 3);
  const int panel = lb >> 1, half = lb & 1;
  const int rowbase = panel * 256;
  const int b = panel >> 3;

  // ---- staging bases (identical to R17)
  const float* hstage = h + (size_t)(rowbase + (tid >> 2)) * NU + (tid & 3) * 16;
  const int rr = tid >> 2, u0 = (tid & 3) * 2;
  const int wby0 = rr * 128 + ((u0 ^ (rr & 7)) << 4);
  const int wby1 = rr * 128 + (((u0 | 1) ^ (rr & 7)) << 4);
  const short* wsrc = WtSw + (size_t)(half * 256 + w * 8 + (lane >> 3)) * NU + (lane & 7) * 8;

  // ---- compute-read offsets (bytes)
  int abase[8], bbase[4], s16[2];
  #pragma unroll
  for (int j = 0; j < 8; ++j) abase[j] = (wr * 128 + j * 16 + lr) * 128;
  #pragma unroll
  for (int j = 0; j < 4; ++j) bbase[j] = (wc * 64 + j * 16 + lr) * 128;
  #pragma unroll
  for (int ks = 0; ks < 2; ++ks) s16[ks] = ((ks * 4 + hi2) ^ (lr & 7)) << 4;

  f32x4 acc[8][4];
  #pragma unroll
  for (int mf = 0; mf < 8; ++mf)
    #pragma unroll
    for (int nf = 0; nf < 4; ++nf)
      acc[mf][nf] = (f32x4){0.f, 0.f, 0.f, 0.f};

  float4 ga0, ga1, ga2, ga3;   // single A stage slot (reused both halves)

  #define STAGEB(nxt, t1, bh)                                                          \
    {                                                                                  \
      _Pragma("unroll")                                                                \
      for (int i = 0; i < 2; ++i)                                                      \
        __builtin_amdgcn_global_load_lds(                                              \
            (const __attribute__((address_space(1))) unsigned*)                        \
                (wsrc + (size_t)((bh) * 128 + i * 64) * NU + (t1) * 64),               \
            (__attribute__((address_space(3))) unsigned*)                              \
                (&Blds[nxt][(bh) * 8192 + i * 4096 + w * 512]), 16, 0, 0);             \
    }

  #define ISSA(t1, ah)                                                                 \
    {                                                                                  \
      const float* p = hstage + (size_t)(ah) * 128 * NU + (t1) * 64;                   \
      ga0 = *reinterpret_cast<const float4*>(p + 0);                                   \
      ga1 = *reinterpret_cast<const float4*>(p + 4);                                   \
      ga2 = *reinterpret_cast<const float4*>(p + 8);                                   \
      ga3 = *reinterpret_cast<const float4*>(p + 12);                                  \
    }

  #define CVTW(nxt, ah)                                                                \
    {                                                                                  \
      char* base = reinterpret_cast<char*>(&Alds[nxt][0]) + (ah) * 16384;              \
      uint4 ua, ub;                                                                    \
      ua.x = pk2(ga0.x, ga0.y); ua.y = pk2(ga0.z, ga0.w);                              \
      ua.z = pk2(ga1.x, ga1.y); ua.w = pk2(ga1.z, ga1.w);                              \
      ub.x = pk2(ga2.x, ga2.y); ub.y = pk2(ga2.z, ga2.w);                              \
      ub.z = pk2(ga3.x, ga3.y); ub.w = pk2(ga3.z, ga3.w);                              \
      *reinterpret_cast<uint4*>(base + wby0) = ua;                                     \
      *reinterpret_cast<uint4*>(base + wby1) = ub;                                     \
    }

  #define READ_A(mh, cur)                                                              \
    _Pragma("unroll")                                                                  \
    for (int mi = 0; mi < 4; ++mi)                                                     \
      _Pragma("unroll")                                                                \
      for (int ks = 0; ks < 2; ++ks)                                                   \
        af[mi][ks] = *reinterpret_cast<const bf16x8*>(                                 \
            reinterpret_cast<const char*>(&Alds[cur][0]) + abase[(mh) * 4 + mi] + s16[ks]);

  #define READ_BQ(BQ, nh, cur)                                                         \
    _Pragma("unroll")                                                                  \
    for (int ni = 0; ni < 2; ++ni)                                                     \
      _Pragma("unroll")                                                                \
      for (int ks = 0; ks < 2; ++ks)                                                   \
        BQ[ni][ks] = *reinterpret_cast<const bf16x8*>(                                 \
            reinterpret_cast<const char*>(&Blds[cur][0]) + bbase[(nh) * 2 + ni] + s16[ks]);

  #define MFMAQ(mh, nh, BQ)                                                            \
    __builtin_amdgcn_s_setprio(1);                                                     \
    _Pragma("unroll")                                                                  \
    for (int ks = 0; ks < 2; ++ks)                                                     \
      _Pragma("unroll")                                                                \
      for (int mi = 0; mi < 4; ++mi)                                                   \
        _Pragma("unroll")                                                              \
        for (int ni = 0; ni < 2; ++ni)                                                 \
          acc[(mh) * 4 + mi][(nh) * 2 + ni] = __builtin_amdgcn_mfma_f32_16x16x32_bf16( \
              af[mi][ks], BQ[ni][ks], acc[(mh) * 4 + mi][(nh) * 2 + ni], 0, 0, 0);     \
    __builtin_amdgcn_s_setprio(0);

  #define BAR                                                                          \
    asm volatile("" ::: "memory");                                                     \
    __builtin_amdgcn_s_barrier();                                                      \
    asm volatile("" ::: "memory");

  // ---- prologue: stage K-tile 0 into buf 0
  ISSA(0, 0);
  STAGEB(0, 0, 0); STAGEB(0, 0, 1);
  CVTW(0, 0);          // waits ga (A half0)
  ISSA(0, 1);
  CVTW(0, 1);
  asm volatile("s_waitcnt vmcnt(0) lgkmcnt(0)" ::: "memory");
  __builtin_amdgcn_s_barrier();
  asm volatile("" ::: "memory");

  // ---- main loop: K-tiles t = 0..6, staging t+1
  #pragma unroll 1
  for (int t = 0; t < 7; ++t) {
    const int cur = t & 1, nxt = cur ^ 1;
    bf16x8 af[4][2], bq0[2][2], bq1[2][2];
    // p0: reads A(0), B(0); issue A(t+1,h0); DMA B(t+1,h0)
    READ_A(0, cur); READ_BQ(bq0, 0, cur);
    ISSA(t + 1, 0);
    STAGEB(nxt, t + 1, 0);
    BAR; MFMAQ(0, 0, bq0); BAR;
    // p1: reads B(1); cvt+write A(t+1,h0)
    READ_BQ(bq1, 1, cur);
    CVTW(nxt, 0);
    BAR; MFMAQ(0, 1, bq1); BAR;
    // p2: reads A(1); issue A(t+1,h1); DMA B(t+1,h1); reuse bq0
    READ_A(1, cur);
    ISSA(t + 1, 1);
    STAGEB(nxt, t + 1, 1);
    BAR; MFMAQ(1, 0, bq0); BAR;
    // p3: cvt+write A(t+1,h1); reuse bq1; boundary drain after MFMA
    CVTW(nxt, 1);
    BAR; MFMAQ(1, 1, bq1);
    asm volatile("s_waitcnt vmcnt(0) lgkmcnt(0)" ::: "memory");
    BAR;
  }

  // ---- last K-tile (t = 7, buf 1): compute only
  {
    bf16x8 af[4][2], bq0[2][2], bq1[2][2];
    READ_A(0, 1); READ_BQ(bq0, 0, 1);
    BAR; MFMAQ(0, 0, bq0); BAR;
    READ_BQ(bq1, 1, 1);
    BAR; MFMAQ(0, 1, bq1); BAR;
    READ_A(1, 1);
    BAR; MFMAQ(1, 0, bq0); BAR;
    BAR; MFMAQ(1, 1, bq1);
  }

  #undef STAGEB
  #undef ISSA
  #undef CVTW
  #undef READ_A
  #undef READ_BQ
  #undef MFMAQ
  #undef BAR

  // ---- epilogue: tanh + V, reduce over wave's 64 cols, atomicAdd rows (R17-verified)
  float fv[4], vv[4];
  #pragma unroll
  for (int nf = 0; nf < 4; ++nf) {
    int col = half * 256 + wc * 64 + nf * 16 + lr;
    fv[nf] = first[b * NU + col];
    vv[nf] = V[col];
  }
  #pragma unroll
  for (int mf = 0; mf < 8; ++mf) {
    f32x4 p;
    #pragma unroll
    for (int r = 0; r < 4; ++r) {
      float s = 0.f;
      #pragma unroll
      for (int nf = 0; nf < 4; ++nf)
        s += vv[nf] * fast_tanh(fv[nf] + acc[mf][nf][r]);
      p[r] = s;
    }
    #pragma unroll
    for (int m = 1; m < 16; m <<= 1) {
      #pragma unroll
      for (int r = 0; r < 4; ++r) p[r] += __shfl_xor(p[r], m, 64);
    }
    if (lr == 0) {
      const int rbase = rowbase + wr * 128 + mf * 16 + hi2 * 4;
      #pragma unroll
      for (int r = 0; r < 4; ++r) atomicAdd(&s0[rbase + r], p[r]);
    }
  }
}

// ---------- softmax over S per batch (in-place in d_out) + context ----------
__global__ __launch_bounds__(256) void softmax_ctx(const float* __restrict__ sp,
                                                   float* __restrict__ out) {
  const int b = blockIdx.x;
  const int t = threadIdx.x;
  float* wgt = out + NBATCH * NU + (size_t)b * SEQ;
  __shared__ float red[4];

  float v[8];
  float mx = -1e30f;
  #pragma unroll
  for (int i = 0; i < 8; ++i) { v[i] = wgt[t + i * 256]; mx = fmaxf(mx, v[i]); }
  #pragma unroll
  for (int m = 1; m < 64; m <<= 1) mx = fmaxf(mx, __shfl_xor(mx, m, 64));
  if ((t & 63) == 0) red[t >> 6] = mx;
  __syncthreads();
  mx = fmaxf(fmaxf(red[0], red[1]), fmaxf(red[2], red[3]));
  __syncthreads();

  float se = 0.f;
  #pragma unroll
  for (int i = 0; i < 8; ++i) { v[i] = __expf(v[i] - mx); se += v[i]; }
  #pragma unroll
  for (int m = 1; m < 64; m <<= 1) se += __shfl_xor(se, m, 64);
  if ((t & 63) == 0) red[t >> 6] = se;
  __syncthreads();
  se = red[0] + red[1] + red[2] + red[3];
  __syncthreads();

  const float inv = 1.0f / se;
  float sw = 0.f;
  #pragma unroll
  for (int i = 0; i < 8; ++i) { float wi = v[i] * inv; wgt[t + i * 256] = wi; sw += wi; }
  #pragma unroll
  for (int m = 1; m < 64; m <<= 1) sw += __shfl_xor(sw, m, 64);
  if ((t & 63) == 0) red[t >> 6] = sw;
  __syncthreads();
  sw = red[0] + red[1] + red[2] + red[3];

  out[b * NU + t]       = sp[b * NU + t] * sw;
  out[b * NU + t + 256] = sp[b * NU + t + 256] * sw;
}

extern "C" void kernel_launch(void* const* d_in, const int* in_sizes, int n_in,
                              void* d_out, int out_size, void* d_ws, size_t ws_size,
                              hipStream_t stream) {
  (void)in_sizes; (void)n_in; (void)out_size; (void)ws_size;
  const float* s_prev = (const float*)d_in[0];
  const float* h      = (const float*)d_in[1];
  const float* Wk     = (const float*)d_in[2];
  const float* Wb     = (const float*)d_in[3];
  const float* Uk     = (const float*)d_in[4];
  const float* Ub     = (const float*)d_in[5];
  const float* Vk     = (const float*)d_in[6];
  // d_in[7] = V_bias: softmax-shift-invariant, does not affect outputs.

  float* out   = (float*)d_out;
  float* first = (float*)d_ws;                    // 64 KB
  short* WtSw  = (short*)((char*)d_ws + 65536);   // 512 KB
  float* s0    = out + NBATCH * NU;               // score accumulator in weights slot

  hipMemsetAsync(s0, 0, (size_t)NBATCH * SEQ * sizeof(float), stream);
  prep_all   <<<1088, 256, 0, stream>>>(Wk, s_prev, Uk, Ub, Wb, WtSw, first);
  attn8      <<< 512, 512, 0, stream>>>(h, WtSw, first, Vk, s0);
  softmax_ctx<<<  32, 256, 0, stream>>>(s_prev, out);
}